// Round 4
// baseline (856.216 us; speedup 1.0000x reference)
//
#include <hip/hip_runtime.h>
#include <hip/hip_bf16.h>

#define NN 100000
#define NE 3200000
#define NG 4096
#define NB 256          // blocks in hist/pairs; NE/NB = 12500 exactly
#define NBK 782         // coarse buckets of 128 nodes
#define NST 4           // channel strips of 16

typedef unsigned short ushort_t;

__device__ __forceinline__ float bf2f(unsigned short u){
  union{unsigned int i; float f;} x; x.i = ((unsigned)u)<<16; return x.f;
}
__device__ __forceinline__ ushort_t f2bf(float f){
  union{float f; unsigned int i;} x; x.f = f;
  unsigned int r = x.i + 0x7fff + ((x.i >> 16) & 1);
  return (ushort_t)(r >> 16);
}

// ---------------- CSR build: hierarchical counting sort ----------------

__global__ __launch_bounds__(512) void k_hist(const int* __restrict__ ei, int* __restrict__ histT){
  __shared__ int lh[NBK];
  int b = blockIdx.x, t = threadIdx.x;
  for (int k=t; k<NBK; k+=512) lh[k]=0;
  __syncthreads();
  int e0 = b*(NE/NB);
  for (int e=e0+t; e<e0+(NE/NB); e+=512) atomicAdd(&lh[ei[NE+e]>>7], 1);
  __syncthreads();
  for (int k=t; k<NBK; k+=512) histT[(size_t)k*NB+b] = lh[k];
}

// one wave per bucket: exclusive scan of NB per-block counts
__global__ __launch_bounds__(256) void k_scanA(int* __restrict__ histT, int* __restrict__ total){
  int wv = blockIdx.x*4 + (threadIdx.x>>6);
  int lane = threadIdx.x & 63;
  if (wv >= NBK) return;
  int* row = histT + (size_t)wv*NB;
  int carry = 0;
  #pragma unroll
  for (int ch=0; ch<NB/64; ++ch){
    int a = row[ch*64+lane];
    int inc = a;
    for (int off=1; off<64; off<<=1){
      int x = __shfl_up(inc, off, 64);
      if (lane >= off) inc += x;
    }
    row[ch*64+lane] = carry + inc - a;       // exclusive
    carry += __shfl(inc, 63, 64);
  }
  if (lane==0) total[wv] = carry;
}

__global__ void k_scanB(const int* __restrict__ total, int* __restrict__ base){
  __shared__ int lds[1024];
  int t = threadIdx.x;
  int v = (t < NBK)? total[t] : 0;
  lds[t] = v; __syncthreads();
  for (int off=1; off<1024; off<<=1){
    int x = (t>=off)? lds[t-off] : 0;
    __syncthreads();
    lds[t] += x;
    __syncthreads();
  }
  if (t < NBK)      base[t]   = lds[t]-v;
  if (t == NBK-1)   base[NBK] = lds[t];      // == NE
}

__global__ __launch_bounds__(512) void k_pairs(const int* __restrict__ ei,
    const int* __restrict__ histT, const int* __restrict__ base,
    int* __restrict__ pairs){
  __shared__ int cur[NBK];
  int b = blockIdx.x, t = threadIdx.x;
  for (int k=t; k<NBK; k+=512) cur[k] = base[k] + histT[(size_t)k*NB + b];
  __syncthreads();
  int e0 = b*(NE/NB);
  for (int e=e0+t; e<e0+(NE/NB); e+=512){
    int src = ei[e], dst = ei[NE+e];
    int p = atomicAdd(&cur[dst>>7], 1);      // LDS atomic
    pairs[p] = (src << 7) | (dst & 127);
  }
}

__global__ __launch_bounds__(256) void k_fine(const int* __restrict__ pairs,
    const int* __restrict__ base, int* __restrict__ csr,
    int* __restrict__ colptr, float* __restrict__ dinv){
  __shared__ int cnt[128], off[128];
  int k = blockIdx.x, t = threadIdx.x;
  if (t < 128) cnt[t] = 0;
  __syncthreads();
  int s = base[k], e = base[k+1];
  for (int i=s+t; i<e; i+=256) atomicAdd(&cnt[pairs[i] & 127], 1);
  __syncthreads();
  int v = (t<128)? cnt[t] : 0;
  if (t<128) off[t] = v;
  __syncthreads();
  for (int o=1; o<128; o<<=1){
    int x = (t>=o && t<128)? off[t-o] : 0;
    __syncthreads();
    if (t<128) off[t] += x;
    __syncthreads();
  }
  int node0 = k*128;
  if (t < 128 && node0+t < NN){
    colptr[node0+t] = s + off[t] - v;
    dinv[node0+t]   = rsqrtf((float)cnt[t] + 1.0f);
  }
  if (k == NBK-1 && t == 0) colptr[NN] = NE;
  __syncthreads();
  if (t < 128) cnt[t] = off[t] - v;
  __syncthreads();
  for (int i=s+t; i<e; i+=256){
    int u = pairs[i];
    int p = s + atomicAdd(&cnt[u & 127], 1);
    csr[p] = u >> 7;
  }
}

// ---------------- GEMM layer0: x[NN][128] fp32 -> hs strip-major bf16 ----------------

__global__ __launch_bounds__(256) void k_gemm0(const float* __restrict__ in_,
    const float* __restrict__ W, const float* __restrict__ dinv,
    ushort_t* __restrict__ out){
  __shared__ float Wl[128*64];
  int t = threadIdx.x;
  for (int i=t; i<128*64; i+=256) Wl[i] = W[i];
  __syncthreads();
  int c  = t & 63;
  int vb = __builtin_amdgcn_readfirstlane((int)(blockIdx.x*16 + (t>>6)*4));
  float acc0=0.f, acc1=0.f, acc2=0.f, acc3=0.f;
  const float4* x0 = (const float4*)(in_ + (size_t)vb*128);
  #pragma unroll 4
  for (int k4=0;k4<32;++k4){
    float4 a0 = x0[k4], a1 = x0[k4+32], a2 = x0[k4+64], a3 = x0[k4+96];
    const float* wr = &Wl[k4*4*64 + c];
    float w0=wr[0], w1=wr[64], w2=wr[128], w3=wr[192];
    acc0 = fmaf(a0.x,w0,fmaf(a0.y,w1,fmaf(a0.z,w2,fmaf(a0.w,w3,acc0))));
    acc1 = fmaf(a1.x,w0,fmaf(a1.y,w1,fmaf(a1.z,w2,fmaf(a1.w,w3,acc1))));
    acc2 = fmaf(a2.x,w0,fmaf(a2.y,w1,fmaf(a2.z,w2,fmaf(a2.w,w3,acc2))));
    acc3 = fmaf(a3.x,w0,fmaf(a3.y,w1,fmaf(a3.z,w2,fmaf(a3.w,w3,acc3))));
  }
  float d0=dinv[vb], d1=dinv[vb+1], d2=dinv[vb+2], d3=dinv[vb+3];
  size_t sb = (size_t)(c>>4)*NN*16 + (c&15);
  out[sb + (size_t)(vb+0)*16]=f2bf(acc0*d0);
  out[sb + (size_t)(vb+1)*16]=f2bf(acc1*d1);
  out[sb + (size_t)(vb+2)*16]=f2bf(acc2*d2);
  out[sb + (size_t)(vb+3)*16]=f2bf(acc3*d3);
}

// ---------------- GEMM layers 1/2: strip-major fp32 in -> strip-major bf16 hs ----------------

__global__ __launch_bounds__(256) void k_gemmS(const float* __restrict__ in_,
    const float* __restrict__ W, const float* __restrict__ dinv,
    ushort_t* __restrict__ out){
  __shared__ float Wl[64*64];
  int t = threadIdx.x;
  for (int i=t; i<64*64; i+=256) Wl[i] = W[i];
  __syncthreads();
  int c  = t & 63;
  int vb = __builtin_amdgcn_readfirstlane((int)(blockIdx.x*16 + (t>>6)*4));
  float acc0=0.f, acc1=0.f, acc2=0.f, acc3=0.f;
  #pragma unroll
  for (int s=0;s<4;++s){
    const float4* xs0 = (const float4*)(in_ + ((size_t)s*NN + vb+0)*16);
    const float4* xs1 = (const float4*)(in_ + ((size_t)s*NN + vb+1)*16);
    const float4* xs2 = (const float4*)(in_ + ((size_t)s*NN + vb+2)*16);
    const float4* xs3 = (const float4*)(in_ + ((size_t)s*NN + vb+3)*16);
    #pragma unroll
    for (int j=0;j<4;++j){
      float4 a0 = xs0[j], a1 = xs1[j], a2 = xs2[j], a3 = xs3[j];
      const float* wr = &Wl[(s*16 + j*4)*64 + c];
      float w0=wr[0], w1=wr[64], w2=wr[128], w3=wr[192];
      acc0 = fmaf(a0.x,w0,fmaf(a0.y,w1,fmaf(a0.z,w2,fmaf(a0.w,w3,acc0))));
      acc1 = fmaf(a1.x,w0,fmaf(a1.y,w1,fmaf(a1.z,w2,fmaf(a1.w,w3,acc1))));
      acc2 = fmaf(a2.x,w0,fmaf(a2.y,w1,fmaf(a2.z,w2,fmaf(a2.w,w3,acc2))));
      acc3 = fmaf(a3.x,w0,fmaf(a3.y,w1,fmaf(a3.z,w2,fmaf(a3.w,w3,acc3))));
    }
  }
  float d0=dinv[vb], d1=dinv[vb+1], d2=dinv[vb+2], d3=dinv[vb+3];
  size_t sb = (size_t)(c>>4)*NN*16 + (c&15);
  out[sb + (size_t)(vb+0)*16]=f2bf(acc0*d0);
  out[sb + (size_t)(vb+1)*16]=f2bf(acc1*d1);
  out[sb + (size_t)(vb+2)*16]=f2bf(acc2*d2);
  out[sb + (size_t)(vb+3)*16]=f2bf(acc3*d3);
}

// ---------------- strip aggregation: one 16-lane group per node ----------------
// outS[s][v][cc] = dinv[v]*(hs_s[v][cc] + sum_e hs_s[src][cc]) + bias[s*16+cc]

__global__ __launch_bounds__(256) void k_aggstrip(const ushort_t* __restrict__ hsS,
    const int* __restrict__ colptr, const int* __restrict__ csr,
    const float* __restrict__ dinv, const float* __restrict__ bias,
    float* __restrict__ outS, float* __restrict__ stats, int s){
  int t = threadIdx.x;
  int cc = t & 15;
  int grp = t >> 4;                          // 0..15
  int vv = blockIdx.x*16 + grp;              // 6250*16 = 100000
  const ushort_t* strip = hsS + (size_t)s*NN*16;
  int e0 = colptr[vv], e1 = colptr[vv+1];
  float acc = bf2f(strip[(size_t)vv*16+cc]);
  int e = e0;
  for (; e < e1 && (e & 3); ++e) acc += bf2f(strip[(size_t)csr[e]*16+cc]);
  for (; e+4 <= e1; e += 4){
    int4 q = *(const int4*)(csr + e);
    float f0 = bf2f(strip[(size_t)q.x*16+cc]);
    float f1 = bf2f(strip[(size_t)q.y*16+cc]);
    float f2 = bf2f(strip[(size_t)q.z*16+cc]);
    float f3 = bf2f(strip[(size_t)q.w*16+cc]);
    acc += (f0+f1)+(f2+f3);
  }
  for (; e<e1; ++e) acc += bf2f(strip[(size_t)csr[e]*16+cc]);
  float o = acc*dinv[vv] + bias[s*16+cc];
  outS[((size_t)s*NN + vv)*16 + cc] = o;
  __shared__ float l1[256], l2[256];
  l1[t]=o; l2[t]=o*o; __syncthreads();
  if (t < 16){
    float a1=0.f, a2=0.f;
    #pragma unroll
    for (int g=0; g<16; ++g){ a1 += l1[g*16+t]; a2 += l2[g*16+t]; }
    float* rep = stats + (size_t)(blockIdx.x & 31)*128;
    atomicAdd(&rep[s*16+t],      a1);
    atomicAdd(&rep[64+s*16+t],   a2);
  }
}

// ---------------- BN coeff + apply ----------------

__global__ void k_bncoeff(const float* __restrict__ stats, const float* __restrict__ g,
                          const float* __restrict__ be, float cnt, float* __restrict__ coeff){
  int c = threadIdx.x;                       // 64
  float s1=0.f, s2=0.f;
  for (int r=0;r<32;++r){ s1 += stats[r*128+c]; s2 += stats[r*128+64+c]; }
  float mu  = s1/cnt;
  float var = s2/cnt - mu*mu;
  float a   = g[c]*rsqrtf(var + 1e-5f);
  coeff[c]    = a;
  coeff[64+c] = be[c] - mu*a;
}

// strip-major buffer: float4 i4 -> strip s = i4/(NN*4), j = i4&3, channels s*16+j*4..+3
__global__ __launch_bounds__(256) void k_bnapply(float* __restrict__ buf, const float* __restrict__ cf){
  int i = blockIdx.x*256 + threadIdx.x;      // NN*16 float4s
  float4 v = ((const float4*)buf)[i];
  int s  = i / (NN*4);
  int c0 = s*16 + (i & 3)*4;
  float a0=cf[c0+0], a1=cf[c0+1], a2=cf[c0+2], a3=cf[c0+3];
  float d0=cf[64+c0+0], d1=cf[64+c0+1], d2=cf[64+c0+2], d3=cf[64+c0+3];
  v.x = fmaxf(fmaf(v.x,a0,d0),0.f);
  v.y = fmaxf(fmaf(v.y,a1,d1),0.f);
  v.z = fmaxf(fmaf(v.z,a2,d2),0.f);
  v.w = fmaxf(fmaf(v.w,a3,d3),0.f);
  ((float4*)buf)[i] = v;
}

// ---------------- pooling / head ----------------

__global__ __launch_bounds__(256) void k_gbounds(const int* __restrict__ batch, int* __restrict__ gstart){
  int g = blockIdx.x*256 + threadIdx.x;      // 4096
  int lo=0, hi=NN;
  while (lo<hi){ int mid=(lo+hi)>>1; if (batch[mid]<g) lo=mid+1; else hi=mid; }
  gstart[g]=lo;
  if (g==0) gstart[NG]=NN;
}

__global__ __launch_bounds__(256) void k_pool(const float* __restrict__ h, const int* __restrict__ gstart,
                                              float* __restrict__ pooled){
  int t=threadIdx.x; int c=t&63;
  int g = __builtin_amdgcn_readfirstlane((int)(blockIdx.x*4 + (t>>6)));
  int s = gstart[g], e = gstart[g+1];
  const float* hp = h + (size_t)(c>>4)*NN*16 + (c&15);
  float acc=0.f;
  for (int v=s; v<e; ++v) acc += hp[(size_t)v*16];
  float inv = 1.0f / fmaxf((float)(e-s), 1.0f);
  pooled[(size_t)g*64+c] = acc*inv;
}

__global__ __launch_bounds__(256) void k_tkern(float* __restrict__ pooled, const float* __restrict__ W1,
                                               const float* __restrict__ b1, float* __restrict__ stats){
  int t=threadIdx.x; int c=t&63;
  int g = __builtin_amdgcn_readfirstlane((int)(blockIdx.x*4 + (t>>6)));
  const float* p = pooled + (size_t)g*64;
  float acc = b1[c];
  #pragma unroll 4
  for (int k=0;k<64;++k) acc = fmaf(p[k], W1[k*64+c], acc);
  pooled[(size_t)g*64+c] = acc;
  float* rep = stats + (size_t)(blockIdx.x & 31)*128;
  atomicAdd(&rep[c],    acc);
  atomicAdd(&rep[64+c], acc*acc);
}

__global__ __launch_bounds__(256) void k_final(const float* __restrict__ tbuf, const float* __restrict__ gcf,
                                               const float* __restrict__ W2, const float* __restrict__ b2,
                                               float* __restrict__ out){
  int t=threadIdx.x; int c=t&63;
  int g = blockIdx.x*4 + (t>>6);
  float tv = tbuf[(size_t)g*64+c];
  float z  = fmaxf(fmaf(tv, gcf[c], gcf[64+c]), 0.f);
  float p  = z * W2[c];
  #pragma unroll
  for (int o=32;o>0;o>>=1) p += __shfl_xor(p, o, 64);
  if (c==0) out[g] = p + b2[0];
}

// ---------------- launch ----------------

extern "C" void kernel_launch(void* const* d_in, const int* in_sizes, int n_in,
                              void* d_out, int out_size, void* d_ws, size_t ws_size,
                              hipStream_t stream) {
  const float* x    = (const float*)d_in[0];
  const int*   ei   = (const int*)d_in[1];
  const int*   batch= (const int*)d_in[2];
  const float* Wc0=(const float*)d_in[3],  *bc0=(const float*)d_in[4];
  const float* g0 =(const float*)d_in[5],  *be0=(const float*)d_in[6];
  const float* Wc1=(const float*)d_in[7],  *bc1=(const float*)d_in[8];
  const float* g1 =(const float*)d_in[9],  *be1=(const float*)d_in[10];
  const float* Wc2=(const float*)d_in[11], *bc2=(const float*)d_in[12];
  const float* g2 =(const float*)d_in[13], *be2=(const float*)d_in[14];
  const float* W1 =(const float*)d_in[15], *b1 =(const float*)d_in[16];
  const float* gf =(const float*)d_in[17], *bf_=(const float*)d_in[18];
  const float* W2 =(const float*)d_in[19], *b2 =(const float*)d_in[20];
  float* out = (float*)d_out;

  char* w = (char*)d_ws;
  float*    stats  = (float*)   (w + 0);          // 4 sets x 32 reps x 128 f [zeroed]
  int*      total  = (int*)     (w + 65536);      // NBK
  int*      base   = (int*)     (w + 68736);      // NBK+1
  int*      colptr = (int*)     (w + 71936);      // NN+1
  float*    dinv   = (float*)   (w + 471952);
  int*      gstart = (int*)     (w + 871952);     // NG+1
  float*    coeff  = (float*)   (w + 888352);
  float*    gcoeff = (float*)   (w + 888864);
  float*    pooled = (float*)   (w + 889392);     // NG x 64
  int*      csr    = (int*)     (w + 1937968);    // NE ints
  ushort_t* bufA   = (ushort_t*)(w + 14737968);   // hs strip-major bf16
  float*    bufB   = (float*)   (w + 27537968);   // h strip-major fp32; ends ~53.1 MB
  int*      histT  = csr;                         // alias: dead before k_fine writes csr
  int*      pairs  = (int*)bufB;                  // alias: dead before bufB first write

  hipMemsetAsync(stats, 0, 65536, stream);

  // CSR build (no global atomics)
  k_hist <<<NB,  512,  0, stream>>>(ei, histT);
  k_scanA<<<196, 256,  0, stream>>>(histT, total);
  k_scanB<<<1,   1024, 0, stream>>>(total, base);
  k_pairs<<<NB,  512,  0, stream>>>(ei, histT, base, pairs);
  k_fine <<<NBK, 256,  0, stream>>>(pairs, base, csr, colptr, dinv);

  // layer 0
  k_gemm0<<<NN/16, 256, 0, stream>>>(x, Wc0, dinv, bufA);
  for (int s=0;s<NST;++s)
    k_aggstrip<<<NN/16, 256, 0, stream>>>(bufA, colptr, csr, dinv, bc0, bufB, stats + 0*4096, s);
  k_bncoeff<<<1, 64, 0, stream>>>(stats + 0*4096, g0, be0, (float)NN, coeff);
  k_bnapply<<<NN*16/256, 256, 0, stream>>>(bufB, coeff);
  // layer 1
  k_gemmS<<<NN/16, 256, 0, stream>>>(bufB, Wc1, dinv, bufA);
  for (int s=0;s<NST;++s)
    k_aggstrip<<<NN/16, 256, 0, stream>>>(bufA, colptr, csr, dinv, bc1, bufB, stats + 1*4096, s);
  k_bncoeff<<<1, 64, 0, stream>>>(stats + 1*4096, g1, be1, (float)NN, coeff);
  k_bnapply<<<NN*16/256, 256, 0, stream>>>(bufB, coeff);
  // layer 2
  k_gemmS<<<NN/16, 256, 0, stream>>>(bufB, Wc2, dinv, bufA);
  for (int s=0;s<NST;++s)
    k_aggstrip<<<NN/16, 256, 0, stream>>>(bufA, colptr, csr, dinv, bc2, bufB, stats + 2*4096, s);
  k_bncoeff<<<1, 64, 0, stream>>>(stats + 2*4096, g2, be2, (float)NN, coeff);
  k_bnapply<<<NN*16/256, 256, 0, stream>>>(bufB, coeff);

  // head
  k_gbounds<<<NG/256, 256, 0, stream>>>(batch, gstart);
  k_pool   <<<NG/4,   256, 0, stream>>>(bufB, gstart, pooled);
  k_tkern  <<<NG/4,   256, 0, stream>>>(pooled, W1, b1, stats + 3*4096);
  k_bncoeff<<<1, 64, 0, stream>>>(stats + 3*4096, gf, bf_, (float)NG, gcoeff);
  k_final  <<<NG/4,   256, 0, stream>>>(pooled, gcoeff, W2, b2, out);
}